// Round 1
// baseline (4445.459 us; speedup 1.0000x reference)
//
#include <hip/hip_runtime.h>
#include <hip/hip_bf16.h>

typedef __hip_bfloat16 bf16;
typedef short v8s __attribute__((ext_vector_type(8)));
typedef float v4f __attribute__((ext_vector_type(4)));

#define BATCH 256
#define SEQ 64
#define INPUT 512
#define HIDDEN 1024
#define CLASSES 1000

// ---------------- conversion kernels (run every call; ws is re-poisoned) ----------------

// x [B,S,I] fp32 -> Xb [S,B,I] bf16
__global__ void conv_x(const float* __restrict__ x, bf16* __restrict__ Xb) {
    int idx = blockIdx.x * 256 + threadIdx.x;        // over 64*256*512 = 2^23
    int t = idx >> 17;                               // / (256*512)
    int r = idx & 131071;
    int b = r >> 9;
    int k = r & 511;
    Xb[idx] = __float2bfloat16(x[(b * SEQ + t) * INPUT + k]);
}

// Build gate-interleaved transposed weights:
// dst[(h*4+g)][k] = (k < K0 ? W[k][g*1024+h] : U[k-K0][g*1024+h]), bf16
// W,U are [K][4096] row-major fp32. grid: (Ktot/32, 4096/32), block (32,8)
__global__ void build_bt(const float* __restrict__ W, const float* __restrict__ U,
                         int K0, int Ktot, bf16* __restrict__ dst) {
    __shared__ float tile[32][33];
    int k0 = blockIdx.x * 32, c0 = blockIdx.y * 32;
    for (int yy = 0; yy < 4; yy++) {
        int kl = threadIdx.y + yy * 8;
        int k = k0 + kl, cc = c0 + threadIdx.x;
        float v = (k < K0) ? W[(size_t)k * 4096 + cc] : U[(size_t)(k - K0) * 4096 + cc];
        tile[kl][threadIdx.x] = v;
    }
    __syncthreads();
    for (int yy = 0; yy < 4; yy++) {
        int cl = threadIdx.y + yy * 8;
        int cc = c0 + cl;
        int row = ((cc & 1023) << 2) | (cc >> 10);   // h*4 + g
        dst[(size_t)row * Ktot + k0 + threadIdx.x] = __float2bfloat16(tile[threadIdx.x][cl]);
    }
}

// Wo [1024][1000] fp32 -> Wot [1024][1024] bf16 transposed, zero-padded rows >= 1000
__global__ void build_wot(const float* __restrict__ Wo, bf16* __restrict__ dst) {
    __shared__ float tile[32][33];
    int k0 = blockIdx.x * 32, n0 = blockIdx.y * 32;
    for (int yy = 0; yy < 4; yy++) {
        int kl = threadIdx.y + yy * 8;
        int k = k0 + kl, n = n0 + threadIdx.x;
        tile[kl][threadIdx.x] = (n < CLASSES) ? Wo[(size_t)k * CLASSES + n] : 0.f;
    }
    __syncthreads();
    for (int yy = 0; yy < 4; yy++) {
        int nl = threadIdx.y + yy * 8;
        int n = n0 + nl;
        dst[(size_t)n * 1024 + k0 + threadIdx.x] = __float2bfloat16(tile[threadIdx.x][nl]);
    }
}

// b [4096] (gate-major chunks) -> br[h*4+g]
__global__ void build_bias(const float* __restrict__ b, float* __restrict__ br) {
    int i = blockIdx.x * 256 + threadIdx.x;          // 4096
    int g = i & 3, h = i >> 2;
    br[i] = b[g * 1024 + h];
}

// ---------------- fused LSTM step ----------------
// Computes z = A0@W + A1@U + b (via pre-built Bt), applies LSTM cell.
// A0: [256][K0] bf16, A1: [256][K1] bf16, Bt: [4096][K0+K1] bf16 (row = h*4+g),
// br: [4096] fp32, C: [256][1024] fp32 in/out, Hout: [256][1024] bf16.
// grid (8, 32), block 256 (4 waves). Tile: 32 batch x 32 h (=128 gate cols).
__global__ __launch_bounds__(256) void lstm_step(
    const bf16* __restrict__ A0, int K0,
    const bf16* __restrict__ A1, int K1,
    const bf16* __restrict__ Bt,
    const float* __restrict__ br,
    float* __restrict__ C,
    bf16* __restrict__ Hout)
{
    const int Ktot = K0 + K1;
    const int m0 = blockIdx.x * 32;
    const int hg0 = blockIdx.y * 32;
    const int nbase = hg0 * 4;

    __shared__ bf16 As[32][40];      // +8 pad
    __shared__ bf16 Bs[128][40];
    __shared__ float Zs[32][132];

    const int tid = threadIdx.x;
    const int lane = tid & 63;
    const int wave = tid >> 6;
    const int col = lane & 15;
    const int quad = lane >> 4;

    v4f acc[2][2] = {};

    const int aml = tid >> 3;            // 0..31
    const int akl = (tid & 7) * 4;       // 0..28
    const int bnl = tid >> 1;            // 0..127
    const int bkl = (tid & 1) * 16;      // 0 or 16

    for (int k0 = 0; k0 < Ktot; k0 += 32) {
        __syncthreads();
        // stage A tile 32x32
        {
            const bf16* Ap; int lda, kk;
            if (k0 < K0) { Ap = A0; lda = K0; kk = k0; }
            else         { Ap = A1; lda = K1; kk = k0 - K0; }
            *(ushort4*)&As[aml][akl] =
                *(const ushort4*)&Ap[(size_t)(m0 + aml) * lda + kk + akl];
        }
        // stage B tile 128x32
        {
            const bf16* src = &Bt[(size_t)(nbase + bnl) * Ktot + k0 + bkl];
            *(uint4*)&Bs[bnl][bkl]     = *(const uint4*)(src);
            *(uint4*)&Bs[bnl][bkl + 8] = *(const uint4*)(src + 8);
        }
        __syncthreads();

        v8s a0 = *(const v8s*)&As[col][quad * 8];
        v8s a1 = *(const v8s*)&As[16 + col][quad * 8];
        const int nb = wave * 32;
        v8s b0 = *(const v8s*)&Bs[nb + col][quad * 8];
        v8s b1 = *(const v8s*)&Bs[nb + 16 + col][quad * 8];
        acc[0][0] = __builtin_amdgcn_mfma_f32_16x16x32_bf16(a0, b0, acc[0][0], 0, 0, 0);
        acc[0][1] = __builtin_amdgcn_mfma_f32_16x16x32_bf16(a0, b1, acc[0][1], 0, 0, 0);
        acc[1][0] = __builtin_amdgcn_mfma_f32_16x16x32_bf16(a1, b0, acc[1][0], 0, 0, 0);
        acc[1][1] = __builtin_amdgcn_mfma_f32_16x16x32_bf16(a1, b1, acc[1][1], 0, 0, 0);
    }

    // write z tiles (+bias) to LDS
    for (int nt = 0; nt < 2; nt++) {
        int ncol = wave * 32 + nt * 16 + col;
        float bias = br[nbase + ncol];
        for (int mt = 0; mt < 2; mt++)
            for (int r = 0; r < 4; r++)
                Zs[mt * 16 + quad * 4 + r][ncol] = acc[mt][nt][r] + bias;
    }
    __syncthreads();

    // elementwise LSTM cell: 1024 (m, h) pairs
    for (int i = 0; i < 4; i++) {
        int idx = tid + i * 256;
        int m = idx >> 5, hl = idx & 31;
        float zi = Zs[m][hl * 4 + 0];
        float zf = Zs[m][hl * 4 + 1];
        float zg = Zs[m][hl * 4 + 2];
        float zo = Zs[m][hl * 4 + 3];
        size_t ci = (size_t)(m0 + m) * HIDDEN + hg0 + hl;
        float cold = C[ci];
        float ig = 1.f / (1.f + __expf(-zi));
        float fg = 1.f / (1.f + __expf(-zf));
        float e2g = __expf(2.f * zg);
        float gg = (e2g - 1.f) / (e2g + 1.f);
        float og = 1.f / (1.f + __expf(-zo));
        float cn = fg * cold + ig * gg;
        float e2c = __expf(2.f * cn);
        float th = (e2c - 1.f) / (e2c + 1.f);
        C[ci] = cn;
        Hout[ci] = __float2bfloat16(og * th);
    }
}

// ---------------- output projection ----------------
// out [256][1000] = H @ Wot^T + bo.  grid (8,16), block 256.
__global__ __launch_bounds__(256) void proj_kernel(
    const bf16* __restrict__ H,      // [256][1024]
    const bf16* __restrict__ Wot,    // [1024][1024] (row n = class, col k)
    const float* __restrict__ bo,    // [1000]
    float* __restrict__ Out)         // [256][1000]
{
    const int m0 = blockIdx.x * 32, n0 = blockIdx.y * 64;
    __shared__ bf16 As[32][40];
    __shared__ bf16 Bs[64][40];
    const int tid = threadIdx.x;
    const int lane = tid & 63;
    const int wave = tid >> 6;
    const int col = lane & 15;
    const int quad = lane >> 4;

    v4f acc[2] = {};
    const int aml = tid >> 3, akl = (tid & 7) * 4;
    const int bnl = tid >> 2, bkl = (tid & 3) * 8;

    for (int k0 = 0; k0 < 1024; k0 += 32) {
        __syncthreads();
        *(ushort4*)&As[aml][akl] = *(const ushort4*)&H[(size_t)(m0 + aml) * 1024 + k0 + akl];
        *(uint4*)&Bs[bnl][bkl]   = *(const uint4*)&Wot[(size_t)(n0 + bnl) * 1024 + k0 + bkl];
        __syncthreads();
        v8s a0 = *(const v8s*)&As[col][quad * 8];
        v8s a1 = *(const v8s*)&As[16 + col][quad * 8];
        v8s b0 = *(const v8s*)&Bs[wave * 16 + col][quad * 8];
        acc[0] = __builtin_amdgcn_mfma_f32_16x16x32_bf16(a0, b0, acc[0], 0, 0, 0);
        acc[1] = __builtin_amdgcn_mfma_f32_16x16x32_bf16(a1, b0, acc[1], 0, 0, 0);
    }
    for (int mt = 0; mt < 2; mt++)
        for (int r = 0; r < 4; r++) {
            int m = m0 + mt * 16 + quad * 4 + r;
            int n = n0 + wave * 16 + col;
            if (n < CLASSES) Out[(size_t)m * CLASSES + n] = acc[mt][r] + bo[n];
        }
}

// ---------------- launcher ----------------

extern "C" void kernel_launch(void* const* d_in, const int* in_sizes, int n_in,
                              void* d_out, int out_size, void* d_ws, size_t ws_size,
                              hipStream_t stream) {
    const float* x  = (const float*)d_in[0];
    const float* W1 = (const float*)d_in[1];
    const float* U1 = (const float*)d_in[2];
    const float* b1 = (const float*)d_in[3];
    const float* W2 = (const float*)d_in[4];
    const float* U2 = (const float*)d_in[5];
    const float* b2 = (const float*)d_in[6];
    const float* Wo = (const float*)d_in[7];
    const float* bo = (const float*)d_in[8];
    float* out = (float*)d_out;

    char* ws = (char*)d_ws;
    size_t off = 0;
    auto alloc = [&](size_t bytes) -> void* {
        void* p = ws + off;
        off += (bytes + 255) & ~(size_t)255;
        return p;
    };
    bf16* Xb   = (bf16*)alloc((size_t)SEQ * BATCH * INPUT * 2);
    bf16* B1t  = (bf16*)alloc((size_t)4096 * 1536 * 2);
    bf16* B2t  = (bf16*)alloc((size_t)4096 * 2048 * 2);
    bf16* Wot  = (bf16*)alloc((size_t)1024 * 1024 * 2);
    float* br1 = (float*)alloc(4096 * 4);
    float* br2 = (float*)alloc(4096 * 4);
    bf16* h1[2] = {(bf16*)alloc(BATCH * HIDDEN * 2), (bf16*)alloc(BATCH * HIDDEN * 2)};
    bf16* h2[2] = {(bf16*)alloc(BATCH * HIDDEN * 2), (bf16*)alloc(BATCH * HIDDEN * 2)};
    float* c1  = (float*)alloc(BATCH * HIDDEN * 4);
    float* c2  = (float*)alloc(BATCH * HIDDEN * 4);

    conv_x<<<(SEQ * BATCH * INPUT) / 256, 256, 0, stream>>>(x, Xb);
    build_bt<<<dim3(1536 / 32, 4096 / 32), dim3(32, 8), 0, stream>>>(W1, U1, 512, 1536, B1t);
    build_bt<<<dim3(2048 / 32, 4096 / 32), dim3(32, 8), 0, stream>>>(W2, U2, 1024, 2048, B2t);
    build_wot<<<dim3(32, 32), dim3(32, 8), 0, stream>>>(Wo, Wot);
    build_bias<<<16, 256, 0, stream>>>(b1, br1);
    build_bias<<<16, 256, 0, stream>>>(b2, br2);
    hipMemsetAsync(h1[0], 0, BATCH * HIDDEN * 2, stream);
    hipMemsetAsync(h2[0], 0, BATCH * HIDDEN * 2, stream);
    hipMemsetAsync(c1, 0, BATCH * HIDDEN * 4, stream);
    hipMemsetAsync(c2, 0, BATCH * HIDDEN * 4, stream);

    for (int t = 0; t < SEQ; t++) {
        int cur = t & 1, nxt = cur ^ 1;
        lstm_step<<<dim3(8, 32), 256, 0, stream>>>(
            Xb + (size_t)t * BATCH * INPUT, 512, h1[cur], 1024, B1t, br1, c1, h1[nxt]);
        lstm_step<<<dim3(8, 32), 256, 0, stream>>>(
            h1[nxt], 1024, h2[cur], 1024, B2t, br2, c2, h2[nxt]);
    }
    // after t=63 (cur=1), final h2 is in h2[0]
    proj_kernel<<<dim3(8, 16), 256, 0, stream>>>(h2[0], Wot, bo, out);
}

// Round 2
// 1590.660 us; speedup vs baseline: 2.7947x; 2.7947x over previous
//
#include <hip/hip_runtime.h>
#include <hip/hip_bf16.h>

typedef __hip_bfloat16 bf16;
typedef short v8s __attribute__((ext_vector_type(8)));
typedef float v4f __attribute__((ext_vector_type(4)));

#define BATCH 256
#define SEQ 64
#define INPUT 512
#define HIDDEN 1024
#define CLASSES 1000

// ============================================================================
// Fragment-linear layouts (all bf16):
//   A-chunk (16 rows m x 32 k): chunk[lane*8+j] = A[m16*16 + (lane&15)][k32*32 + (lane>>4)*8 + j]
//   B-chunk (16 cols n x 32 k): chunk[lane*8+j] = W[k32*32 + (lane>>4)*8 + j][ncol]
//   A wave reads its whole fragment with ONE global_load_dwordx4 (base + lane*16).
// Xfrag:  [t][m16(16)][k32(16)][512]
// h-frag: [m16(16)][k32(32)][512]
// Bf:     [n16(256: g*64+h16)][k32(nT)][512]   (gate-strip order)
// Wof:    [n16(64)][k32(32)][512]
// ============================================================================

// ---------------- x [B,S,I] fp32 -> Xfrag ----------------
__global__ __launch_bounds__(256) void conv_x(const float* __restrict__ x,
                                              bf16* __restrict__ Xf) {
    int gid = blockIdx.x * 256 + threadIdx.x;     // 1,048,576 chunks-of-8
    int lane = gid & 63;
    int k32 = (gid >> 6) & 15;
    int m16 = (gid >> 10) & 15;
    int tt  = gid >> 14;                           // 0..63
    int row = lane & 15, quad = lane >> 4;
    int b_ = m16 * 16 + row;
    int k  = k32 * 32 + quad * 8;
    const float* src = x + ((size_t)(b_ * SEQ + tt) * INPUT + k);
    float4 v0 = *(const float4*)src;
    float4 v1 = *(const float4*)(src + 4);
    bf16 o[8] = {__float2bfloat16(v0.x), __float2bfloat16(v0.y),
                 __float2bfloat16(v0.z), __float2bfloat16(v0.w),
                 __float2bfloat16(v1.x), __float2bfloat16(v1.y),
                 __float2bfloat16(v1.z), __float2bfloat16(v1.w)};
    bf16* dst = Xf + (size_t)(tt * 256 + m16 * 16 + k32) * 512 + lane * 8;
    *(v8s*)dst = *(v8s*)o;
}

// ---------------- [W;U] fp32 -> Bf fragment-linear ----------------
// grid (Ktot/64, 64, 4), block 256. blockIdx.z = gate, .y = h16 strip, .x = k-tile.
__global__ __launch_bounds__(256) void build_bf(const float* __restrict__ W,
                                                const float* __restrict__ U,
                                                int K0, int nT,
                                                bf16* __restrict__ dst) {
    __shared__ float tile[64][17];
    const int g = blockIdx.z, h16 = blockIdx.y, kt = blockIdx.x;
    const int k0 = kt * 64;
    const int cb = g * 1024 + h16 * 16;
    const int tid = threadIdx.x;
#pragma unroll
    for (int i = 0; i < 4; i++) {
        int idx = tid + i * 256;                  // 0..1023
        int kl = idx >> 4, c = idx & 15;
        int k = k0 + kl;
        float v = (k < K0) ? W[(size_t)k * 4096 + cb + c]
                           : U[(size_t)(k - K0) * 4096 + cb + c];
        tile[kl][c] = v;
    }
    __syncthreads();
    if (tid < 128) {
        int k32l = tid >> 6, l = tid & 63;
        int col = l & 15, quad = l >> 4;
        bf16 o[8];
#pragma unroll
        for (int j = 0; j < 8; j++)
            o[j] = __float2bfloat16(tile[k32l * 32 + quad * 8 + j][col]);
        int n16 = g * 64 + h16;
        int k32 = kt * 2 + k32l;
        *(v8s*)(dst + (size_t)(n16 * nT + k32) * 512 + l * 8) = *(v8s*)o;
    }
}

// ---------------- Wo [1024][1000] fp32 -> Wof fragment-linear (zero-pad) ----
__global__ __launch_bounds__(256) void build_wof(const float* __restrict__ Wo,
                                                 bf16* __restrict__ dst) {
    __shared__ float tile[64][17];
    const int h16 = blockIdx.y, kt = blockIdx.x;
    const int k0 = kt * 64, nb = h16 * 16;
    const int tid = threadIdx.x;
#pragma unroll
    for (int i = 0; i < 4; i++) {
        int idx = tid + i * 256;
        int kl = idx >> 4, c = idx & 15;
        int k = k0 + kl;
        float v = (nb + c < CLASSES) ? Wo[(size_t)k * CLASSES + nb + c] : 0.f;
        tile[kl][c] = v;
    }
    __syncthreads();
    if (tid < 128) {
        int k32l = tid >> 6, l = tid & 63;
        int col = l & 15, quad = l >> 4;
        bf16 o[8];
#pragma unroll
        for (int j = 0; j < 8; j++)
            o[j] = __float2bfloat16(tile[k32l * 32 + quad * 8 + j][col]);
        int k32 = kt * 2 + k32l;
        *(v8s*)(dst + (size_t)(h16 * 32 + k32) * 512 + l * 8) = *(v8s*)o;
    }
}

// ---------------- fused phase: L1(t=p) and L2(t=p-1) concurrently ----------
// grid 512 blocks x 256 threads (4 waves). Block = 64 batch x 16 h x 4 gates.
// Pure streaming K-loop: global_load_dwordx4 + mfma, ring prefetch 8, no LDS.
__global__ __launch_bounds__(256, 2) void lstm_phase(
    int p,
    const bf16* __restrict__ Xf,
    const bf16* __restrict__ Bf1, const bf16* __restrict__ Bf2,
    const float* __restrict__ bias1, const float* __restrict__ bias2,
    bf16* __restrict__ h1f0, bf16* __restrict__ h1f1,
    bf16* __restrict__ h2f0, bf16* __restrict__ h2f1,
    const bf16* __restrict__ hz,
    float* __restrict__ c1, float* __restrict__ c2)
{
    const int b = blockIdx.x;
    const int hblk = b & 63;         // b%8 = hblk%8 -> per-XCD weight slice ~3.6 MB
    const int rem = b >> 6;
    const int layer = rem & 1;
    const int mt = rem >> 1;         // 0..3

    int t, nA, nT;
    const bf16 *A0base, *A1base, *Bf;
    const float* bias;
    bf16* hout;
    float* cptr;
    if (layer == 0) {
        t = p; if (t >= SEQ) return;
        nT = 48; nA = 16; Bf = Bf1; bias = bias1; cptr = c1;
        A0base = Xf + (size_t)t * (BATCH * INPUT);
        A1base = (t == 0) ? hz : ((t & 1) ? h1f0 : h1f1);   // h1f[(t-1)&1]
        hout = (t & 1) ? h1f1 : h1f0;                        // h1f[t&1]
    } else {
        t = p - 1; if (t < 0) return;
        nT = 64; nA = 32; Bf = Bf2; bias = bias2; cptr = c2;
        A0base = (t & 1) ? h1f1 : h1f0;                      // h1f[t&1]
        A1base = (t == 0) ? hz : ((t & 1) ? h2f0 : h2f1);    // h2f[(t-1)&1]
        hout = (t & 1) ? h2f1 : h2f0;                        // h2f[t&1]
    }

    const int tid = threadIdx.x;
    const int lane = tid & 63;
    const int wave = tid >> 6;
    const int mw = wave >> 1, nw = wave & 1;
    const int col = lane & 15, quad = lane >> 4;

    const int m16 = mt * 4 + mw * 2;
    const bf16* ax0 = A0base + (size_t)(m16 * nA) * 512 + lane * 8;
    const bf16* ax1 = A0base + (size_t)((m16 + 1) * nA) * 512 + lane * 8;
    const bf16* ah0 = A1base + (size_t)(m16 * 32) * 512 + lane * 8;
    const bf16* ah1 = A1base + (size_t)((m16 + 1) * 32) * 512 + lane * 8;
    const int g0 = nw * 2, g1 = g0 + 1;
    const bf16* bb0 = Bf + (size_t)((g0 * 64 + hblk) * nT) * 512 + lane * 8;
    const bf16* bb1 = Bf + (size_t)((g1 * 64 + hblk) * nT) * 512 + lane * 8;

    v4f acc00{}, acc01{}, acc10{}, acc11{};
    v8s ra0[8], ra1[8], rb0[8], rb1[8];

#define ISSUE(KK, SLOT) do {                                                     \
    const int kk_ = (KK);                                                        \
    const bf16* pa0_ = (kk_ < nA) ? (ax0 + kk_ * 512) : (ah0 + (kk_ - nA) * 512);\
    const bf16* pa1_ = (kk_ < nA) ? (ax1 + kk_ * 512) : (ah1 + (kk_ - nA) * 512);\
    ra0[SLOT] = *(const v8s*)pa0_;                                               \
    ra1[SLOT] = *(const v8s*)pa1_;                                               \
    rb0[SLOT] = *(const v8s*)(bb0 + kk_ * 512);                                  \
    rb1[SLOT] = *(const v8s*)(bb1 + kk_ * 512);                                  \
} while (0)

#pragma unroll
    for (int u = 0; u < 8; u++) ISSUE(u, u);

    for (int base = 0; base < nT; base += 8) {
#pragma unroll
        for (int u = 0; u < 8; u++) {
            acc00 = __builtin_amdgcn_mfma_f32_16x16x32_bf16(ra0[u], rb0[u], acc00, 0, 0, 0);
            acc01 = __builtin_amdgcn_mfma_f32_16x16x32_bf16(ra0[u], rb1[u], acc01, 0, 0, 0);
            acc10 = __builtin_amdgcn_mfma_f32_16x16x32_bf16(ra1[u], rb0[u], acc10, 0, 0, 0);
            acc11 = __builtin_amdgcn_mfma_f32_16x16x32_bf16(ra1[u], rb1[u], acc11, 0, 0, 0);
            const int k2 = base + u + 8;
            if (k2 < nT) ISSUE(k2, u);
        }
    }
#undef ISSUE

    // ---- epilogue: z (+bias) -> LDS, fused LSTM cell ----
    __shared__ float Zs[64][68];     // cols: hl*4 + gate
    const float bv0 = bias[g0 * 1024 + hblk * 16 + col];
    const float bv1 = bias[g1 * 1024 + hblk * 16 + col];
    const int zr = mw * 32 + quad * 4;
#pragma unroll
    for (int r = 0; r < 4; r++) {
        Zs[zr + r][col * 4 + g0]      = acc00[r] + bv0;
        Zs[zr + r][col * 4 + g1]      = acc01[r] + bv1;
        Zs[zr + 16 + r][col * 4 + g0] = acc10[r] + bv0;
        Zs[zr + 16 + r][col * 4 + g1] = acc11[r] + bv1;
    }
    __syncthreads();

    if (tid < 128) {
        const int m = tid >> 1, ch = tid & 1;
        const int mg = mt * 64 + m;
        const int hg = hblk * 16 + ch * 8;
        float* cp = cptr + (size_t)mg * HIDDEN + hg;
        float4 cv0 = *(float4*)cp;
        float4 cv1 = *(float4*)(cp + 4);
        float cold[8] = {cv0.x, cv0.y, cv0.z, cv0.w, cv1.x, cv1.y, cv1.z, cv1.w};
        float cnew[8];
        bf16 hv[8];
#pragma unroll
        for (int hh = 0; hh < 8; hh++) {
            const int zc = (ch * 8 + hh) * 4;
            float zi = Zs[m][zc], zf = Zs[m][zc + 1];
            float zg = Zs[m][zc + 2], zo = Zs[m][zc + 3];
            float ig = 1.f / (1.f + __expf(-zi));
            float fg = 1.f / (1.f + __expf(-zf));
            float e2g = __expf(2.f * zg);
            float gg = (e2g - 1.f) / (e2g + 1.f);
            float og = 1.f / (1.f + __expf(-zo));
            float cn = fg * cold[hh] + ig * gg;
            float e2c = __expf(2.f * cn);
            float th = (e2c - 1.f) / (e2c + 1.f);
            cnew[hh] = cn;
            hv[hh] = __float2bfloat16(og * th);
        }
        *(float4*)cp = make_float4(cnew[0], cnew[1], cnew[2], cnew[3]);
        *(float4*)(cp + 4) = make_float4(cnew[4], cnew[5], cnew[6], cnew[7]);
        const size_t hoff = (size_t)(((mg >> 4) * 32 + (hg >> 5)) * 64
                                     + ((hg >> 3) & 3) * 16 + (mg & 15)) * 8;
        *(v8s*)(hout + hoff) = *(v8s*)hv;
    }
}

// ---------------- projection: out = h2 @ Wo + bo ----------------
// grid (4,16), block 256. Same streaming structure, K=1024 (32 chunks).
__global__ __launch_bounds__(256, 2) void proj_kernel(
    const bf16* __restrict__ H,      // h2 final, fragment-linear
    const bf16* __restrict__ Wof,
    const float* __restrict__ bo,
    float* __restrict__ Out)
{
    const int mblk = blockIdx.x, nblk = blockIdx.y;
    const int tid = threadIdx.x;
    const int lane = tid & 63;
    const int wave = tid >> 6;
    const int mw = wave >> 1, nw = wave & 1;
    const int col = lane & 15, quad = lane >> 4;

    const int m16 = mblk * 4 + mw * 2;
    const bf16* ah0 = H + (size_t)(m16 * 32) * 512 + lane * 8;
    const bf16* ah1 = H + (size_t)((m16 + 1) * 32) * 512 + lane * 8;
    const int n16a = nblk * 4 + nw * 2, n16b = n16a + 1;
    const bf16* bb0 = Wof + (size_t)(n16a * 32) * 512 + lane * 8;
    const bf16* bb1 = Wof + (size_t)(n16b * 32) * 512 + lane * 8;

    v4f acc00{}, acc01{}, acc10{}, acc11{};
    v8s ra0[8], ra1[8], rb0[8], rb1[8];

#define ISSUE(KK, SLOT) do {                          \
    const int kk_ = (KK);                             \
    ra0[SLOT] = *(const v8s*)(ah0 + kk_ * 512);       \
    ra1[SLOT] = *(const v8s*)(ah1 + kk_ * 512);       \
    rb0[SLOT] = *(const v8s*)(bb0 + kk_ * 512);       \
    rb1[SLOT] = *(const v8s*)(bb1 + kk_ * 512);       \
} while (0)

#pragma unroll
    for (int u = 0; u < 8; u++) ISSUE(u, u);

    for (int base = 0; base < 32; base += 8) {
#pragma unroll
        for (int u = 0; u < 8; u++) {
            acc00 = __builtin_amdgcn_mfma_f32_16x16x32_bf16(ra0[u], rb0[u], acc00, 0, 0, 0);
            acc01 = __builtin_amdgcn_mfma_f32_16x16x32_bf16(ra0[u], rb1[u], acc01, 0, 0, 0);
            acc10 = __builtin_amdgcn_mfma_f32_16x16x32_bf16(ra1[u], rb0[u], acc10, 0, 0, 0);
            acc11 = __builtin_amdgcn_mfma_f32_16x16x32_bf16(ra1[u], rb1[u], acc11, 0, 0, 0);
            const int k2 = base + u + 8;
            if (k2 < 32) ISSUE(k2, u);
        }
    }
#undef ISSUE

    const int n0 = n16a * 16 + col, n1 = n16b * 16 + col;
    const float bo0 = (n0 < CLASSES) ? bo[n0] : 0.f;
    const float bo1 = (n1 < CLASSES) ? bo[n1] : 0.f;
#pragma unroll
    for (int i = 0; i < 2; i++) {
        const int row = mblk * 64 + mw * 32 + i * 16 + quad * 4;
        v4f a0 = i ? acc10 : acc00;
        v4f a1 = i ? acc11 : acc01;
#pragma unroll
        for (int r = 0; r < 4; r++) {
            if (n0 < CLASSES) Out[(size_t)(row + r) * CLASSES + n0] = a0[r] + bo0;
            if (n1 < CLASSES) Out[(size_t)(row + r) * CLASSES + n1] = a1[r] + bo1;
        }
    }
}

// ---------------- launcher ----------------
extern "C" void kernel_launch(void* const* d_in, const int* in_sizes, int n_in,
                              void* d_out, int out_size, void* d_ws, size_t ws_size,
                              hipStream_t stream) {
    const float* x  = (const float*)d_in[0];
    const float* W1 = (const float*)d_in[1];
    const float* U1 = (const float*)d_in[2];
    const float* b1 = (const float*)d_in[3];
    const float* W2 = (const float*)d_in[4];
    const float* U2 = (const float*)d_in[5];
    const float* b2 = (const float*)d_in[6];
    const float* Wo = (const float*)d_in[7];
    const float* bo = (const float*)d_in[8];
    float* out = (float*)d_out;

    char* ws = (char*)d_ws;
    size_t off = 0;
    auto alloc = [&](size_t bytes) -> void* {
        void* p = ws + off;
        off += (bytes + 255) & ~(size_t)255;
        return p;
    };
    bf16* Xf   = (bf16*)alloc((size_t)SEQ * BATCH * INPUT * 2);        // 16.8 MB
    bf16* Bf1  = (bf16*)alloc((size_t)256 * 48 * 512 * 2);             // 12.6 MB
    bf16* Bf2  = (bf16*)alloc((size_t)256 * 64 * 512 * 2);             // 16.8 MB
    bf16* Wof  = (bf16*)alloc((size_t)64 * 32 * 512 * 2);              // 2 MB
    bf16* h1f0 = (bf16*)alloc((size_t)BATCH * HIDDEN * 2);
    bf16* h1f1 = (bf16*)alloc((size_t)BATCH * HIDDEN * 2);
    bf16* h2f0 = (bf16*)alloc((size_t)BATCH * HIDDEN * 2);
    bf16* h2f1 = (bf16*)alloc((size_t)BATCH * HIDDEN * 2);
    bf16* hz   = (bf16*)alloc((size_t)BATCH * HIDDEN * 2);
    float* c1  = (float*)alloc((size_t)BATCH * HIDDEN * 4);
    float* c2  = (float*)alloc((size_t)BATCH * HIDDEN * 4);

    hipMemsetAsync(hz, 0, (size_t)BATCH * HIDDEN * 2, stream);
    hipMemsetAsync(c1, 0, (size_t)BATCH * HIDDEN * 4, stream);
    hipMemsetAsync(c2, 0, (size_t)BATCH * HIDDEN * 4, stream);

    conv_x<<<4096, 256, 0, stream>>>(x, Xf);
    build_bf<<<dim3(24, 64, 4), 256, 0, stream>>>(W1, U1, 512, 48, Bf1);
    build_bf<<<dim3(32, 64, 4), 256, 0, stream>>>(W2, U2, 1024, 64, Bf2);
    build_wof<<<dim3(16, 64), 256, 0, stream>>>(Wo, Wof);

    for (int p = 0; p <= SEQ; p++) {
        lstm_phase<<<512, 256, 0, stream>>>(p, Xf, Bf1, Bf2, b1, b2,
                                            h1f0, h1f1, h2f0, h2f1, hz, c1, c2);
    }
    // final h2 written at t=63 -> h2f[63&1] = h2f1
    proj_kernel<<<dim3(4, 16), 256, 0, stream>>>(h2f1, Wof, bo, out);
}